// Round 13
// baseline (166.899 us; speedup 1.0000x reference)
//
#include <hip/hip_runtime.h>
#include <hip/hip_bf16.h>

typedef __hip_bfloat16 bf16;
typedef __attribute__((ext_vector_type(8))) short s16x8;
typedef __attribute__((ext_vector_type(4))) float f32x4;

// Y-staging swizzle on 128B rows (R8-proven, 16B granule)
#define SWZY(c) ((((c) ^ ((c) >> 3) ^ ((c) >> 4)) & 7) << 4)
// S/carry region: 16B-block swizzle including SEGMENT bits (c>>5) so the
// scan's c=32s+i access pattern spreads across all banks (2-way = free).
// Local mode ml (0..31) of row c lives at dword DWP(ml,c); 16B blocks stay
// contiguous (low 2 bits of ml untouched) so gemm3's b128 reads work.
#define GB(c)  ((((c) ^ ((c) >> 3) ^ ((c) >> 5)) & 7))
#define DWP(ml, c) (((ml) & 3) | (((((ml) >> 2) ^ GB(c)) & 7) << 2))

__device__ __forceinline__ unsigned short f2b(float x){
    __hip_bfloat16 h = __float2bfloat16(x);
    return __builtin_bit_cast(unsigned short, h);
}
__device__ __forceinline__ float b2f(unsigned short s){
    unsigned int u = (unsigned int)s << 16;
    return __builtin_bit_cast(float, u);
}

// ---------------- K0: per-h tables via direct complex exp ------------------
// Qh[h][n2=128][t=64]     : Q[2n][t]=Re r^{63-t}, Q[2n+1][t]=Im r^{63-t} (bf16)
// Pmh/Pml[h][j=64][n2=128]: Pm[j][2n]=Re(2Ck r^{j+1}), [2n+1]=-Im(...)   (hi+lo)
// Klh/Kll[h][j=64][t=64]  : Kd[j-t] (t<=j) + D*delta(t==j)  [row j]      (hi+lo)
// rLtab[h][n][2]=r^64 ; rStab[h][n][2]=r^2048  (f32, scan: 32-chunk segments)
__global__ __launch_bounds__(256) void k0_setup(const float* __restrict__ log_dt,
        const float* __restrict__ C_ri, const float* __restrict__ log_A_real,
        const float* __restrict__ A_imag, const float* __restrict__ Dp,
        float* __restrict__ rLtab, float* __restrict__ rStab,
        short* __restrict__ Qh,
        short* __restrict__ Pmh, short* __restrict__ Pml,
        short* __restrict__ Klh, short* __restrict__ Kll)
{
    __shared__ float arr[64][65];   // Pm_re staging: arr[j][n] = Re(2Ck r^{j+1})
    __shared__ float a0[64];        // 2*Re(Ck)
    __shared__ float kd[64];
    int h = blockIdx.x;
    int tid = threadIdx.x;
    int n = tid & 63, g = tid >> 6;
    int hn = h * 64 + n;
    double dtd  = exp((double)log_dt[h]);
    float  Aref = -expf(log_A_real[hn]);
    double Ared = (double)Aref;
    double Aimd = (double)A_imag[hn];
    double adt  = Aimd * dtd;                 // angle per unit exponent
    float  mdt  = (float)(Ared * dtd);        // log-magnitude per unit exponent
    auto cexp = [&](float e, float& re, float& im){
        double a = adt * (double)e;
        double k = floor(a * 0.15915494309189535);
        float ang = (float)(a - k * 6.283185307179586);
        float si, co;
        __sincosf(ang, &si, &co);
        float mag = expf(mdt * e);
        re = mag * co; im = mag * si;
    };
    // Ck = C * (r-1)/A
    float rre, rim; cexp(1.f, rre, rim);
    float Cre = C_ri[2 * hn], Cim = C_ri[2 * hn + 1];
    float emre = rre - 1.f, emim = rim;
    float inva2 = 1.f / (Aref * Aref + (float)(Aimd * Aimd));
    float qre_ = (emre * Aref + emim * (float)Aimd) * inva2;
    float qim_ = (emim * Aref - emre * (float)Aimd) * inva2;
    float ckre = Cre * qre_ - Cim * qim_;
    float ckim = Cre * qim_ + Cim * qre_;
    // Q rows 2n,2n+1 for t in [16g,16g+16)
    {
        short* q0 = Qh + (size_t)h * 8192 + (2 * n) * 64;
        short* q1 = q0 + 64;
        for (int t = 16 * g; t < 16 * g + 16; ++t) {
            float pre, pim; cexp((float)(63 - t), pre, pim);
            q0[t] = (short)f2b(pre);
            q1[t] = (short)f2b(pim);
        }
    }
    if (g == 0) {   // r^64
        float pre, pim; cexp(64.f, pre, pim);
        rLtab[2 * hn] = pre; rLtab[2 * hn + 1] = pim;
    }
    if (g == 1) {   // r^2048 (segment hop: 32 chunks x 64)
        float pre, pim; cexp(2048.f, pre, pim);
        rStab[2 * hn] = pre; rStab[2 * hn + 1] = pim;
    }
    if (g == 2) a0[n] = 2.f * ckre;
    // Pm rows j in [16g,16g+16)
    {
        short* pmh = Pmh + (size_t)h * 8192;
        short* pml = Pml + (size_t)h * 8192;
        for (int j = 16 * g; j < 16 * g + 16; ++j) {
            float pre, pim; cexp((float)(j + 1), pre, pim);
            float wre = 2.f * (ckre * pre - ckim * pim);
            float wim = 2.f * (ckre * pim + ckim * pre);
            unsigned short h0 = f2b(wre), h1 = f2b(-wim);
            pmh[j * 128 + 2 * n]     = (short)h0;
            pml[j * 128 + 2 * n]     = (short)f2b(wre - b2f(h0));
            pmh[j * 128 + 2 * n + 1] = (short)h1;
            pml[j * 128 + 2 * n + 1] = (short)f2b(-wim - b2f(h1));
            arr[j][n] = wre;
        }
    }
    __syncthreads();
    if (tid < 64) {                 // Kd[d]
        int d = tid;
        float s = 0.f;
        if (d == 0) { for (int k = 0; k < 64; ++k) s += a0[k]; }
        else        { for (int k = 0; k < 64; ++k) s += arr[d - 1][k]; }
        kd[d] = s;
    }
    __syncthreads();
    // Klow ROW j=n (storage [j][t]), D on diagonal
    {
        float Dh = Dp[h];
        short* klh = Klh + (size_t)h * 4096 + n * 64;   // row j=n
        short* kll = Kll + (size_t)h * 4096 + n * 64;
        for (int t = 16 * g; t < 16 * g + 16; ++t) {
            if (t <= n) {
                float v = kd[n - t] + ((t == n) ? Dh : 0.f);
                unsigned short h0 = f2b(v);
                klh[t] = (short)h0;
                kll[t] = (short)f2b(v - b2f(h0));
            } else { klh[t] = 0; kll[t] = 0; }
        }
    }
}

// ---------------- fused: conv(+D) + 2x[gemm1 half | scan | gemm3] ----------
// block=(b,h); 4 waves; wave w owns c-rows [64w,64w+64).  LDS = 32KB single
// region [256 rows][128B], in-place S->carry per half (each (row,dword) owned
// by exactly one scan thread). 5 barriers.
// Register budget: xl is used ONLY by the conv phase (gemm1 drops the qh*xl
// terms: ~0.4% of S, same order as the accepted bf16-S rounding). Live set in
// the long phase chain = xh(32)+acc(64)+temps ~120; peak (conv) ~150.
// __launch_bounds__(256,3): unified cap 170 >= peak -> 3 waves/SIMD (R12's
// 192-reg state forced 2). If allocator cliffs (VGPR=64), revert to (256,2).
__global__ __launch_bounds__(256, 3) void k_fused(const float* __restrict__ u,
        const int* __restrict__ length,
        const float* __restrict__ rLtab, const float* __restrict__ rStab,
        const short* __restrict__ Qh,
        const short* __restrict__ Pmh, const short* __restrict__ Pml,
        const short* __restrict__ Klh, const short* __restrict__ Kll,
        bf16* __restrict__ y, double* __restrict__ stats)
{
    __shared__ __align__(16) unsigned char lds[32768];
    int bh = blockIdx.x;
    int b = bh >> 6, h = bh & 63;
    int tid = threadIdx.x;
    int w = tid >> 6, lane = tid & 63;
    int lo = lane & 15, hi = lane >> 4;
    int len = length[b];
    const float* ub = u + (size_t)bh * 16384;

    // ---- X fragments, hi+lo split (masked u)
    s16x8 xh[4][2], xl[4][2];
    #pragma unroll
    for (int ct = 0; ct < 4; ++ct) {
        int c = w * 64 + ct * 16 + lo;
        #pragma unroll
        for (int kt = 0; kt < 2; ++kt) {
            int gidx = c * 64 + kt * 32 + hi * 8;
            float4 v0 = *(const float4*)(ub + gidx);
            float4 v1 = *(const float4*)(ub + gidx + 4);
            float xv[8] = {v0.x, v0.y, v0.z, v0.w, v1.x, v1.y, v1.z, v1.w};
            s16x8 fh, fl;
            #pragma unroll
            for (int e = 0; e < 8; ++e) {
                float xm = (gidx + e < len) ? xv[e] : 0.f;
                unsigned short h0 = f2b(xm);
                fh[e] = (short)h0;
                fl[e] = (short)f2b(xm - b2f(h0));
            }
            xh[ct][kt] = fh;
            xl[ct][kt] = fl;
        }
    }

    // ---- local conv (+ D via baked diagonal): Y[c][j] += X[c][t]*Kl'[t][j]
    f32x4 acc[4][4];
    #pragma unroll
    for (int ct = 0; ct < 4; ++ct)
        #pragma unroll
        for (int jt = 0; jt < 4; ++jt)
            acc[ct][jt] = f32x4{0.f, 0.f, 0.f, 0.f};
    {
        const short* klhb = Klh + (size_t)h * 4096;
        const short* kllb = Kll + (size_t)h * 4096;
        #pragma unroll
        for (int kt = 0; kt < 2; ++kt) {
            #pragma unroll
            for (int jt = 0; jt < 4; ++jt) {
                s16x8 kfh = *(const s16x8*)(klhb + (jt * 16 + lo) * 64 + kt * 32 + hi * 8);
                s16x8 kfl = *(const s16x8*)(kllb + (jt * 16 + lo) * 64 + kt * 32 + hi * 8);
                #pragma unroll
                for (int ct = 0; ct < 4; ++ct) {
                    acc[ct][jt] = __builtin_amdgcn_mfma_f32_16x16x32_bf16(xh[ct][kt], kfh, acc[ct][jt], 0, 0, 0);
                    acc[ct][jt] = __builtin_amdgcn_mfma_f32_16x16x32_bf16(xh[ct][kt], kfl, acc[ct][jt], 0, 0, 0);
                    acc[ct][jt] = __builtin_amdgcn_mfma_f32_16x16x32_bf16(xl[ct][kt], kfh, acc[ct][jt], 0, 0, 0);
                }
            }
        }
    }

    // GEMM1 for half hh (32 modes = 64 n2-rows): S = Qh*Xh -> bf16 dwords
    auto gemm1 = [&](int hh){
        const short* qb = Qh + (size_t)h * 8192 + (hh * 64) * 64;
        #pragma unroll
        for (int mt = 0; mt < 4; ++mt) {
            s16x8 q0 = *(const s16x8*)(qb + (mt * 16 + lo) * 64 + hi * 8);
            s16x8 q1 = *(const s16x8*)(qb + (mt * 16 + lo) * 64 + 32 + hi * 8);
            #pragma unroll
            for (int ct = 0; ct < 4; ++ct) {
                f32x4 sc = f32x4{0.f, 0.f, 0.f, 0.f};
                sc = __builtin_amdgcn_mfma_f32_16x16x32_bf16(q0, xh[ct][0], sc, 0, 0, 0);
                sc = __builtin_amdgcn_mfma_f32_16x16x32_bf16(q1, xh[ct][1], sc, 0, 0, 0);
                int c = w * 64 + ct * 16 + lo;
                // rows n2 = 16mt+4hi+{0..3} -> local modes ml0=8mt+2hi, ml0+1
                int ml0 = 8 * mt + 2 * hi;
                unsigned int p0 = (unsigned)f2b(sc[0]) | ((unsigned)f2b(sc[1]) << 16);
                unsigned int p1 = (unsigned)f2b(sc[2]) | ((unsigned)f2b(sc[3]) << 16);
                unsigned long long pp = (unsigned long long)p0 | ((unsigned long long)p1 << 32);
                *(unsigned long long*)(lds + c * 128 + DWP(ml0, c) * 4) = pp;
            }
        }
    };
    // GEMM3 for half hh: Y[c][j] += carry[c][ml] * Pm[64hh+n2][j]
    auto gemm3 = [&](int hh){
        const short* pmhb = Pmh + (size_t)h * 8192 + hh * 64;
        const short* pmlb = Pml + (size_t)h * 8192 + hh * 64;
        #pragma unroll
        for (int kt2 = 0; kt2 < 2; ++kt2) {
            s16x8 af[4];
            #pragma unroll
            for (int ct = 0; ct < 4; ++ct) {
                int c = w * 64 + ct * 16 + lo;
                int blk = (4 * kt2 + hi) ^ GB(c);
                af[ct] = *(const s16x8*)(lds + c * 128 + blk * 16);
            }
            #pragma unroll
            for (int jt = 0; jt < 4; ++jt) {
                s16x8 pfh = *(const s16x8*)(pmhb + (jt * 16 + lo) * 128 + kt2 * 32 + hi * 8);
                s16x8 pfl = *(const s16x8*)(pmlb + (jt * 16 + lo) * 128 + kt2 * 32 + hi * 8);
                #pragma unroll
                for (int ct = 0; ct < 4; ++ct) {
                    acc[ct][jt] = __builtin_amdgcn_mfma_f32_16x16x32_bf16(af[ct], pfh, acc[ct][jt], 0, 0, 0);
                    acc[ct][jt] = __builtin_amdgcn_mfma_f32_16x16x32_bf16(af[ct], pfl, acc[ct][jt], 0, 0, 0);
                }
            }
        }
    };
    // scan for half hh: 32 modes x 8 segments of 32 chunks; in-place carries.
    auto scan = [&](int hh){
        int m = tid >> 3, s = tid & 7;
        int gm = (h * 64 + hh * 32 + m) * 2;
        float r64re = rLtab[gm], r64im = rLtab[gm + 1];
        float pre = rStab[gm],  pim = rStab[gm + 1];     // r^2048
        // pass 1: segment end-state (32 chunks)
        float ere = 0.f, eim = 0.f;
        #pragma unroll
        for (int i = 0; i < 32; ++i) {
            int c = 32 * s + i;
            unsigned int v = *(const unsigned int*)(lds + c * 128 + DWP(m, c) * 4);
            float vre = b2f((unsigned short)v);
            float vim = b2f((unsigned short)(v >> 16));
            float nre = fmaf(r64re, ere, fmaf(-r64im, eim, vre));
            eim = fmaf(r64re, eim, fmaf(r64im, ere, vim));
            ere = nre;
        }
        // in-wave Kogge-Stone over 8 segments (d = 1,2,4; p <- p^2 each step)
        #pragma unroll
        for (int d = 1; d < 8; d <<= 1) {
            float orr = __shfl(ere, (lane - d) & 63, 64);
            float oii = __shfl(eim, (lane - d) & 63, 64);
            if (s >= d) {
                float nre = fmaf(pre, orr, fmaf(-pim, oii, ere));
                eim = fmaf(pre, oii, fmaf(pim, orr, eim));
                ere = nre;
            }
            float t2 = pre * pre - pim * pim;
            pim = 2.f * pre * pim;
            pre = t2;
        }
        // exclusive carry-in = inclusive of segment s-1
        float cire = __shfl(ere, (lane - 1) & 63, 64);
        float ciim = __shfl(eim, (lane - 1) & 63, 64);
        if (s == 0) { cire = 0.f; ciim = 0.f; }
        // pass 2: overwrite S dword with carry (same thread owns (row,dword))
        #pragma unroll
        for (int i = 0; i < 32; ++i) {
            int c = 32 * s + i;
            unsigned char* p = lds + c * 128 + DWP(m, c) * 4;
            unsigned int v = *(const unsigned int*)p;
            float vre = b2f((unsigned short)v);
            float vim = b2f((unsigned short)(v >> 16));
            *(unsigned int*)p = (unsigned)f2b(cire) | ((unsigned)f2b(ciim) << 16);
            float nre = fmaf(r64re, cire, fmaf(-r64im, ciim, vre));
            ciim = fmaf(r64re, ciim, fmaf(r64im, cire, vim));
            cire = nre;
        }
    };

    gemm1(0);
    __syncthreads();
    scan(0);
    __syncthreads();
    gemm3(0);        // reads wave-local rows...
    gemm1(1);        // ...then overwrites wave-local rows (same-wave order)
    __syncthreads();
    scan(1);
    __syncthreads();
    gemm3(1);

    // ---- Y staging (wave-local rows): acc -> bf16 [256][128B]
    #pragma unroll
    for (int ct = 0; ct < 4; ++ct) {
        #pragma unroll
        for (int jt = 0; jt < 4; ++jt) {
            int j = jt * 16 + lo;
            #pragma unroll
            for (int rg = 0; rg < 4; ++rg) {
                int c = w * 64 + ct * 16 + hi * 4 + rg;
                *(unsigned short*)(lds + c * 128 + ((2 * j) ^ SWZY(c))) = f2b(acc[ct][jt][rg]);
            }
        }
    }
    __syncthreads();

    // ---- epilogue: mask, coalesced y store, f32 stats -> f64 atomics
    float s1 = 0.f, s2 = 0.f;
    short* yg = (short*)y + (size_t)bh * 16384;
    #pragma unroll
    for (int k = 0; k < 8; ++k) {
        int eidx = (k * 256 + tid) * 8;
        int row = eidx >> 6;
        int byt = ((eidx & 63) * 2) ^ SWZY(row);
        s16x8 yv = *(const s16x8*)(lds + row * 128 + byt);
        s16x8 o;
        #pragma unroll
        for (int e = 0; e < 8; ++e) {
            float vv = b2f((unsigned short)yv[e]);
            vv = (eidx + e < len) ? vv : 0.f;
            o[e] = (short)f2b(vv);
            s1 += vv;
            s2 = fmaf(vv, vv, s2);
        }
        *(s16x8*)(yg + eidx) = o;
    }
    #pragma unroll
    for (int off = 32; off > 0; off >>= 1) {
        s1 += __shfl_down(s1, off, 64);
        s2 += __shfl_down(s2, off, 64);
    }
    if (lane == 0) {
        atomicAdd(&stats[2 * h],     (double)s1);
        atomicAdd(&stats[2 * h + 1], (double)s2);
    }
}

// ---------------- K4: layernorm + FiLM + tanh + residual (8 elems/thread) --
__global__ __launch_bounds__(256) void k4_final(const float* __restrict__ u,
        const bf16* __restrict__ y, const float* __restrict__ cond,
        const float* __restrict__ fw, const float* __restrict__ fb,
        const double* __restrict__ stats, float* __restrict__ out)
{
    int tid = threadIdx.x;
    size_t idx8 = ((size_t)blockIdx.x * 256 + tid) * 8;
    int bh = (int)(idx8 >> 14);
    int b = bh >> 6, h = bh & 63;
    __shared__ float gg[2];
    if (tid == 0) {
        float g = fb[h], bb = fb[64 + h];
        #pragma unroll
        for (int k = 0; k < 3; ++k) {
            g  = fmaf(cond[b * 3 + k], fw[h * 3 + k], g);
            bb = fmaf(cond[b * 3 + k], fw[(64 + h) * 3 + k], bb);
        }
        gg[0] = g; gg[1] = bb;
    }
    __syncthreads();
    double inv = 1.0 / (16.0 * 16384.0);
    double mean_d = stats[2 * h] * inv;
    double var_d  = stats[2 * h + 1] * inv - mean_d * mean_d;
    float mean = (float)mean_d;
    float rstd = rsqrtf((float)var_d + 1e-5f);
    float gv = gg[0], bv = gg[1];
    float4 u0 = *(const float4*)(u + idx8);
    float4 u1 = *(const float4*)(u + idx8 + 4);
    s16x8 yv = *(const s16x8*)((const short*)y + idx8);
    float uv[8] = {u0.x, u0.y, u0.z, u0.w, u1.x, u1.y, u1.z, u1.w};
    float ov[8];
    #pragma unroll
    for (int e = 0; e < 8; ++e) {
        float z = fmaf((b2f((unsigned short)yv[e]) - mean) * rstd, gv, bv);
        ov[e] = uv[e] + tanhf(z);
    }
    *(float4*)(out + idx8)     = float4{ov[0], ov[1], ov[2], ov[3]};
    *(float4*)(out + idx8 + 4) = float4{ov[4], ov[5], ov[6], ov[7]};
}

// ---------------------------------------------------------------------------
extern "C" void kernel_launch(void* const* d_in, const int* in_sizes, int n_in,
                              void* d_out, int out_size, void* d_ws, size_t ws_size,
                              hipStream_t stream)
{
    const float* u           = (const float*)d_in[0];
    const float* cond        = (const float*)d_in[1];
    const int*   length      = (const int*)  d_in[2];
    const float* log_dt      = (const float*)d_in[3];
    const float* C_ri        = (const float*)d_in[4];
    const float* log_A_real  = (const float*)d_in[5];
    const float* A_imag      = (const float*)d_in[6];
    const float* D           = (const float*)d_in[7];
    const float* film_w      = (const float*)d_in[8];
    const float* film_b      = (const float*)d_in[9];
    float* out = (float*)d_out;

    char* w = (char*)d_ws;
    bf16*   y      = (bf16*)w;                    // 33,554,432 B
    short*  Qh     = (short*)(w + 33554432);      //  1,048,576 B
    short*  Pmh    = (short*)(w + 34603008);      //  1,048,576 B
    short*  Pml    = (short*)(w + 35651584);      //  1,048,576 B
    short*  Klh    = (short*)(w + 36700160);      //    524,288 B
    short*  Kll    = (short*)(w + 37224448);      //    524,288 B
    float*  rLtab  = (float*)(w + 37748736);      //     32,768 B
    float*  rStab  = (float*)(w + 37781504);      //     32,768 B
    double* stats  = (double*)(w + 37814272);     //      1,024 B   (~37.8 MB)

    hipMemsetAsync(stats, 0, 1024, stream);
    hipLaunchKernelGGL(k0_setup, dim3(64),   dim3(256), 0, stream,
                       log_dt, C_ri, log_A_real, A_imag, D,
                       rLtab, rStab, Qh, Pmh, Pml, Klh, Kll);
    hipLaunchKernelGGL(k_fused,  dim3(1024), dim3(256), 0, stream,
                       u, length, rLtab, rStab, Qh, Pmh, Pml, Klh, Kll, y, stats);
    hipLaunchKernelGGL(k4_final, dim3(8192), dim3(256), 0, stream,
                       u, y, cond, film_w, film_b, stats, out);
}

// Round 14
// 107.903 us; speedup vs baseline: 1.5468x; 1.5468x over previous
//
#include <hip/hip_runtime.h>
#include <hip/hip_bf16.h>

typedef __hip_bfloat16 bf16;
typedef __attribute__((ext_vector_type(8))) short s16x8;
typedef __attribute__((ext_vector_type(4))) float f32x4;

// Y-staging swizzle on 128B rows (R8-proven, 16B granule)
#define SWZY(c) ((((c) ^ ((c) >> 3) ^ ((c) >> 4)) & 7) << 4)
// S/carry region: 16B-block swizzle including SEGMENT bits (c>>5) so the
// scan's c=32s+i access pattern spreads across all banks (2-way = free).
// Local mode ml (0..31) of row c lives at dword DWP(ml,c); 16B blocks stay
// contiguous (low 2 bits of ml untouched) so gemm3's b128 reads work.
// [R13-measured: SQ_LDS_BANK_CONFLICT 5.4M -> 786K vs R12's GSW]
#define GB(c)  ((((c) ^ ((c) >> 3) ^ ((c) >> 5)) & 7))
#define DWP(ml, c) (((ml) & 3) | (((((ml) >> 2) ^ GB(c)) & 7) << 2))

__device__ __forceinline__ unsigned short f2b(float x){
    __hip_bfloat16 h = __float2bfloat16(x);
    return __builtin_bit_cast(unsigned short, h);
}
__device__ __forceinline__ float b2f(unsigned short s){
    unsigned int u = (unsigned int)s << 16;
    return __builtin_bit_cast(float, u);
}

// ---------------- K0: per-h tables via direct complex exp ------------------
// Qh[h][n2=128][t=64]     : Q[2n][t]=Re r^{63-t}, Q[2n+1][t]=Im r^{63-t} (bf16)
// Pmh/Pml[h][j=64][n2=128]: Pm[j][2n]=Re(2Ck r^{j+1}), [2n+1]=-Im(...)   (hi+lo)
// Klh/Kll[h][j=64][t=64]  : Kd[j-t] (t<=j) + D*delta(t==j)  [row j]      (hi+lo)
// rLtab[h][n][2]=r^64 ; rStab[h][n][2]=r^2048  (f32, scan: 32-chunk segments)
__global__ __launch_bounds__(256) void k0_setup(const float* __restrict__ log_dt,
        const float* __restrict__ C_ri, const float* __restrict__ log_A_real,
        const float* __restrict__ A_imag, const float* __restrict__ Dp,
        float* __restrict__ rLtab, float* __restrict__ rStab,
        short* __restrict__ Qh,
        short* __restrict__ Pmh, short* __restrict__ Pml,
        short* __restrict__ Klh, short* __restrict__ Kll)
{
    __shared__ float arr[64][65];   // Pm_re staging: arr[j][n] = Re(2Ck r^{j+1})
    __shared__ float a0[64];        // 2*Re(Ck)
    __shared__ float kd[64];
    int h = blockIdx.x;
    int tid = threadIdx.x;
    int n = tid & 63, g = tid >> 6;
    int hn = h * 64 + n;
    double dtd  = exp((double)log_dt[h]);
    float  Aref = -expf(log_A_real[hn]);
    double Ared = (double)Aref;
    double Aimd = (double)A_imag[hn];
    double adt  = Aimd * dtd;                 // angle per unit exponent
    float  mdt  = (float)(Ared * dtd);        // log-magnitude per unit exponent
    auto cexp = [&](float e, float& re, float& im){
        double a = adt * (double)e;
        double k = floor(a * 0.15915494309189535);
        float ang = (float)(a - k * 6.283185307179586);
        float si, co;
        __sincosf(ang, &si, &co);
        float mag = expf(mdt * e);
        re = mag * co; im = mag * si;
    };
    // Ck = C * (r-1)/A
    float rre, rim; cexp(1.f, rre, rim);
    float Cre = C_ri[2 * hn], Cim = C_ri[2 * hn + 1];
    float emre = rre - 1.f, emim = rim;
    float inva2 = 1.f / (Aref * Aref + (float)(Aimd * Aimd));
    float qre_ = (emre * Aref + emim * (float)Aimd) * inva2;
    float qim_ = (emim * Aref - emre * (float)Aimd) * inva2;
    float ckre = Cre * qre_ - Cim * qim_;
    float ckim = Cre * qim_ + Cim * qre_;
    // Q rows 2n,2n+1 for t in [16g,16g+16)
    {
        short* q0 = Qh + (size_t)h * 8192 + (2 * n) * 64;
        short* q1 = q0 + 64;
        for (int t = 16 * g; t < 16 * g + 16; ++t) {
            float pre, pim; cexp((float)(63 - t), pre, pim);
            q0[t] = (short)f2b(pre);
            q1[t] = (short)f2b(pim);
        }
    }
    if (g == 0) {   // r^64
        float pre, pim; cexp(64.f, pre, pim);
        rLtab[2 * hn] = pre; rLtab[2 * hn + 1] = pim;
    }
    if (g == 1) {   // r^2048 (segment hop: 32 chunks x 64)
        float pre, pim; cexp(2048.f, pre, pim);
        rStab[2 * hn] = pre; rStab[2 * hn + 1] = pim;
    }
    if (g == 2) a0[n] = 2.f * ckre;
    // Pm rows j in [16g,16g+16)
    {
        short* pmh = Pmh + (size_t)h * 8192;
        short* pml = Pml + (size_t)h * 8192;
        for (int j = 16 * g; j < 16 * g + 16; ++j) {
            float pre, pim; cexp((float)(j + 1), pre, pim);
            float wre = 2.f * (ckre * pre - ckim * pim);
            float wim = 2.f * (ckre * pim + ckim * pre);
            unsigned short h0 = f2b(wre), h1 = f2b(-wim);
            pmh[j * 128 + 2 * n]     = (short)h0;
            pml[j * 128 + 2 * n]     = (short)f2b(wre - b2f(h0));
            pmh[j * 128 + 2 * n + 1] = (short)h1;
            pml[j * 128 + 2 * n + 1] = (short)f2b(-wim - b2f(h1));
            arr[j][n] = wre;
        }
    }
    __syncthreads();
    if (tid < 64) {                 // Kd[d]
        int d = tid;
        float s = 0.f;
        if (d == 0) { for (int k = 0; k < 64; ++k) s += a0[k]; }
        else        { for (int k = 0; k < 64; ++k) s += arr[d - 1][k]; }
        kd[d] = s;
    }
    __syncthreads();
    // Klow ROW j=n (storage [j][t]), D on diagonal
    {
        float Dh = Dp[h];
        short* klh = Klh + (size_t)h * 4096 + n * 64;   // row j=n
        short* kll = Kll + (size_t)h * 4096 + n * 64;
        for (int t = 16 * g; t < 16 * g + 16; ++t) {
            if (t <= n) {
                float v = kd[n - t] + ((t == n) ? Dh : 0.f);
                unsigned short h0 = f2b(v);
                klh[t] = (short)h0;
                kll[t] = (short)f2b(v - b2f(h0));
            } else { klh[t] = 0; kll[t] = 0; }
        }
    }
}

// ---------------- fused: conv(+D) + 2x[gemm1 half | scan | gemm3] ----------
// block=(b,h); 4 waves; wave w owns c-rows [64w,64w+64).  LDS = 32KB single
// region [256 rows][128B], in-place S->carry per half. 5 barriers.
// __launch_bounds__(256,2): the ONLY no-spill setting — 4x confirmed
// (R6 (256,4)->spill, R9 (512,4)->spill, R11 (256,4)->spill, R13 (256,3)->
// spill at VGPR 84 / 210MB scratch; R7/R8/R12 (256,2) clean at VGPR 120-128).
__global__ __launch_bounds__(256, 2) void k_fused(const float* __restrict__ u,
        const int* __restrict__ length,
        const float* __restrict__ rLtab, const float* __restrict__ rStab,
        const short* __restrict__ Qh,
        const short* __restrict__ Pmh, const short* __restrict__ Pml,
        const short* __restrict__ Klh, const short* __restrict__ Kll,
        bf16* __restrict__ y, double* __restrict__ stats)
{
    __shared__ __align__(16) unsigned char lds[32768];
    int bh = blockIdx.x;
    int b = bh >> 6, h = bh & 63;
    int tid = threadIdx.x;
    int w = tid >> 6, lane = tid & 63;
    int lo = lane & 15, hi = lane >> 4;
    int len = length[b];
    const float* ub = u + (size_t)bh * 16384;

    // ---- X fragments, hi+lo split (masked u)
    s16x8 xh[4][2], xl[4][2];
    #pragma unroll
    for (int ct = 0; ct < 4; ++ct) {
        int c = w * 64 + ct * 16 + lo;
        #pragma unroll
        for (int kt = 0; kt < 2; ++kt) {
            int gidx = c * 64 + kt * 32 + hi * 8;
            float4 v0 = *(const float4*)(ub + gidx);
            float4 v1 = *(const float4*)(ub + gidx + 4);
            float xv[8] = {v0.x, v0.y, v0.z, v0.w, v1.x, v1.y, v1.z, v1.w};
            s16x8 fh, fl;
            #pragma unroll
            for (int e = 0; e < 8; ++e) {
                float xm = (gidx + e < len) ? xv[e] : 0.f;
                unsigned short h0 = f2b(xm);
                fh[e] = (short)h0;
                fl[e] = (short)f2b(xm - b2f(h0));
            }
            xh[ct][kt] = fh;
            xl[ct][kt] = fl;
        }
    }

    // ---- local conv (+ D via baked diagonal): Y[c][j] += X[c][t]*Kl'[t][j]
    f32x4 acc[4][4];
    #pragma unroll
    for (int ct = 0; ct < 4; ++ct)
        #pragma unroll
        for (int jt = 0; jt < 4; ++jt)
            acc[ct][jt] = f32x4{0.f, 0.f, 0.f, 0.f};
    {
        const short* klhb = Klh + (size_t)h * 4096;
        const short* kllb = Kll + (size_t)h * 4096;
        #pragma unroll
        for (int kt = 0; kt < 2; ++kt) {
            #pragma unroll
            for (int jt = 0; jt < 4; ++jt) {
                s16x8 kfh = *(const s16x8*)(klhb + (jt * 16 + lo) * 64 + kt * 32 + hi * 8);
                s16x8 kfl = *(const s16x8*)(kllb + (jt * 16 + lo) * 64 + kt * 32 + hi * 8);
                #pragma unroll
                for (int ct = 0; ct < 4; ++ct) {
                    acc[ct][jt] = __builtin_amdgcn_mfma_f32_16x16x32_bf16(xh[ct][kt], kfh, acc[ct][jt], 0, 0, 0);
                    acc[ct][jt] = __builtin_amdgcn_mfma_f32_16x16x32_bf16(xh[ct][kt], kfl, acc[ct][jt], 0, 0, 0);
                    acc[ct][jt] = __builtin_amdgcn_mfma_f32_16x16x32_bf16(xl[ct][kt], kfh, acc[ct][jt], 0, 0, 0);
                }
            }
        }
    }

    // GEMM1 for half hh (32 modes = 64 n2-rows): S = Qh*Xh -> bf16 dwords
    // (qh*xl terms dropped: ~0.4% of S, same order as accepted bf16-S rounding)
    auto gemm1 = [&](int hh){
        const short* qb = Qh + (size_t)h * 8192 + (hh * 64) * 64;
        #pragma unroll
        for (int mt = 0; mt < 4; ++mt) {
            s16x8 q0 = *(const s16x8*)(qb + (mt * 16 + lo) * 64 + hi * 8);
            s16x8 q1 = *(const s16x8*)(qb + (mt * 16 + lo) * 64 + 32 + hi * 8);
            #pragma unroll
            for (int ct = 0; ct < 4; ++ct) {
                f32x4 sc = f32x4{0.f, 0.f, 0.f, 0.f};
                sc = __builtin_amdgcn_mfma_f32_16x16x32_bf16(q0, xh[ct][0], sc, 0, 0, 0);
                sc = __builtin_amdgcn_mfma_f32_16x16x32_bf16(q1, xh[ct][1], sc, 0, 0, 0);
                int c = w * 64 + ct * 16 + lo;
                // rows n2 = 16mt+4hi+{0..3} -> local modes ml0=8mt+2hi, ml0+1
                int ml0 = 8 * mt + 2 * hi;
                unsigned int p0 = (unsigned)f2b(sc[0]) | ((unsigned)f2b(sc[1]) << 16);
                unsigned int p1 = (unsigned)f2b(sc[2]) | ((unsigned)f2b(sc[3]) << 16);
                unsigned long long pp = (unsigned long long)p0 | ((unsigned long long)p1 << 32);
                *(unsigned long long*)(lds + c * 128 + DWP(ml0, c) * 4) = pp;
            }
        }
    };
    // GEMM3 for half hh: Y[c][j] += carry[c][ml] * Pm[64hh+n2][j]
    auto gemm3 = [&](int hh){
        const short* pmhb = Pmh + (size_t)h * 8192 + hh * 64;
        const short* pmlb = Pml + (size_t)h * 8192 + hh * 64;
        #pragma unroll
        for (int kt2 = 0; kt2 < 2; ++kt2) {
            s16x8 af[4];
            #pragma unroll
            for (int ct = 0; ct < 4; ++ct) {
                int c = w * 64 + ct * 16 + lo;
                int blk = (4 * kt2 + hi) ^ GB(c);
                af[ct] = *(const s16x8*)(lds + c * 128 + blk * 16);
            }
            #pragma unroll
            for (int jt = 0; jt < 4; ++jt) {
                s16x8 pfh = *(const s16x8*)(pmhb + (jt * 16 + lo) * 128 + kt2 * 32 + hi * 8);
                s16x8 pfl = *(const s16x8*)(pmlb + (jt * 16 + lo) * 128 + kt2 * 32 + hi * 8);
                #pragma unroll
                for (int ct = 0; ct < 4; ++ct) {
                    acc[ct][jt] = __builtin_amdgcn_mfma_f32_16x16x32_bf16(af[ct], pfh, acc[ct][jt], 0, 0, 0);
                    acc[ct][jt] = __builtin_amdgcn_mfma_f32_16x16x32_bf16(af[ct], pfl, acc[ct][jt], 0, 0, 0);
                }
            }
        }
    };
    // scan for half hh: 32 modes x 8 segments of 32 chunks; in-place carries.
    auto scan = [&](int hh){
        int m = tid >> 3, s = tid & 7;
        int gm = (h * 64 + hh * 32 + m) * 2;
        float r64re = rLtab[gm], r64im = rLtab[gm + 1];
        float pre = rStab[gm],  pim = rStab[gm + 1];     // r^2048
        // pass 1: segment end-state (32 chunks)
        float ere = 0.f, eim = 0.f;
        #pragma unroll
        for (int i = 0; i < 32; ++i) {
            int c = 32 * s + i;
            unsigned int v = *(const unsigned int*)(lds + c * 128 + DWP(m, c) * 4);
            float vre = b2f((unsigned short)v);
            float vim = b2f((unsigned short)(v >> 16));
            float nre = fmaf(r64re, ere, fmaf(-r64im, eim, vre));
            eim = fmaf(r64re, eim, fmaf(r64im, ere, vim));
            ere = nre;
        }
        // in-wave Kogge-Stone over 8 segments (d = 1,2,4; p <- p^2 each step)
        #pragma unroll
        for (int d = 1; d < 8; d <<= 1) {
            float orr = __shfl(ere, (lane - d) & 63, 64);
            float oii = __shfl(eim, (lane - d) & 63, 64);
            if (s >= d) {
                float nre = fmaf(pre, orr, fmaf(-pim, oii, ere));
                eim = fmaf(pre, oii, fmaf(pim, orr, eim));
                ere = nre;
            }
            float t2 = pre * pre - pim * pim;
            pim = 2.f * pre * pim;
            pre = t2;
        }
        // exclusive carry-in = inclusive of segment s-1
        float cire = __shfl(ere, (lane - 1) & 63, 64);
        float ciim = __shfl(eim, (lane - 1) & 63, 64);
        if (s == 0) { cire = 0.f; ciim = 0.f; }
        // pass 2: overwrite S dword with carry (same thread owns (row,dword))
        #pragma unroll
        for (int i = 0; i < 32; ++i) {
            int c = 32 * s + i;
            unsigned char* p = lds + c * 128 + DWP(m, c) * 4;
            unsigned int v = *(const unsigned int*)p;
            float vre = b2f((unsigned short)v);
            float vim = b2f((unsigned short)(v >> 16));
            *(unsigned int*)p = (unsigned)f2b(cire) | ((unsigned)f2b(ciim) << 16);
            float nre = fmaf(r64re, cire, fmaf(-r64im, ciim, vre));
            ciim = fmaf(r64re, ciim, fmaf(r64im, cire, vim));
            cire = nre;
        }
    };

    gemm1(0);
    __syncthreads();
    scan(0);
    __syncthreads();
    gemm3(0);        // reads wave-local rows...
    gemm1(1);        // ...then overwrites wave-local rows (same-wave order)
    __syncthreads();
    scan(1);
    __syncthreads();
    gemm3(1);

    // ---- Y staging (wave-local rows): acc -> bf16 [256][128B]
    #pragma unroll
    for (int ct = 0; ct < 4; ++ct) {
        #pragma unroll
        for (int jt = 0; jt < 4; ++jt) {
            int j = jt * 16 + lo;
            #pragma unroll
            for (int rg = 0; rg < 4; ++rg) {
                int c = w * 64 + ct * 16 + hi * 4 + rg;
                *(unsigned short*)(lds + c * 128 + ((2 * j) ^ SWZY(c))) = f2b(acc[ct][jt][rg]);
            }
        }
    }
    __syncthreads();

    // ---- epilogue: mask, coalesced y store, f32 stats -> f64 atomics
    float s1 = 0.f, s2 = 0.f;
    short* yg = (short*)y + (size_t)bh * 16384;
    #pragma unroll
    for (int k = 0; k < 8; ++k) {
        int eidx = (k * 256 + tid) * 8;
        int row = eidx >> 6;
        int byt = ((eidx & 63) * 2) ^ SWZY(row);
        s16x8 yv = *(const s16x8*)(lds + row * 128 + byt);
        s16x8 o;
        #pragma unroll
        for (int e = 0; e < 8; ++e) {
            float vv = b2f((unsigned short)yv[e]);
            vv = (eidx + e < len) ? vv : 0.f;
            o[e] = (short)f2b(vv);
            s1 += vv;
            s2 = fmaf(vv, vv, s2);
        }
        *(s16x8*)(yg + eidx) = o;
    }
    #pragma unroll
    for (int off = 32; off > 0; off >>= 1) {
        s1 += __shfl_down(s1, off, 64);
        s2 += __shfl_down(s2, off, 64);
    }
    if (lane == 0) {
        atomicAdd(&stats[2 * h],     (double)s1);
        atomicAdd(&stats[2 * h + 1], (double)s2);
    }
}

// ---------------- K4: layernorm + FiLM + tanh + residual (8 elems/thread) --
__global__ __launch_bounds__(256) void k4_final(const float* __restrict__ u,
        const bf16* __restrict__ y, const float* __restrict__ cond,
        const float* __restrict__ fw, const float* __restrict__ fb,
        const double* __restrict__ stats, float* __restrict__ out)
{
    int tid = threadIdx.x;
    size_t idx8 = ((size_t)blockIdx.x * 256 + tid) * 8;
    int bh = (int)(idx8 >> 14);
    int b = bh >> 6, h = bh & 63;
    __shared__ float gg[2];
    if (tid == 0) {
        float g = fb[h], bb = fb[64 + h];
        #pragma unroll
        for (int k = 0; k < 3; ++k) {
            g  = fmaf(cond[b * 3 + k], fw[h * 3 + k], g);
            bb = fmaf(cond[b * 3 + k], fw[(64 + h) * 3 + k], bb);
        }
        gg[0] = g; gg[1] = bb;
    }
    __syncthreads();
    double inv = 1.0 / (16.0 * 16384.0);
    double mean_d = stats[2 * h] * inv;
    double var_d  = stats[2 * h + 1] * inv - mean_d * mean_d;
    float mean = (float)mean_d;
    float rstd = rsqrtf((float)var_d + 1e-5f);
    float gv = gg[0], bv = gg[1];
    float4 u0 = *(const float4*)(u + idx8);
    float4 u1 = *(const float4*)(u + idx8 + 4);
    s16x8 yv = *(const s16x8*)((const short*)y + idx8);
    float uv[8] = {u0.x, u0.y, u0.z, u0.w, u1.x, u1.y, u1.z, u1.w};
    float ov[8];
    #pragma unroll
    for (int e = 0; e < 8; ++e) {
        float z = fmaf((b2f((unsigned short)yv[e]) - mean) * rstd, gv, bv);
        ov[e] = uv[e] + tanhf(z);
    }
    *(float4*)(out + idx8)     = float4{ov[0], ov[1], ov[2], ov[3]};
    *(float4*)(out + idx8 + 4) = float4{ov[4], ov[5], ov[6], ov[7]};
}

// ---------------------------------------------------------------------------
extern "C" void kernel_launch(void* const* d_in, const int* in_sizes, int n_in,
                              void* d_out, int out_size, void* d_ws, size_t ws_size,
                              hipStream_t stream)
{
    const float* u           = (const float*)d_in[0];
    const float* cond        = (const float*)d_in[1];
    const int*   length      = (const int*)  d_in[2];
    const float* log_dt      = (const float*)d_in[3];
    const float* C_ri        = (const float*)d_in[4];
    const float* log_A_real  = (const float*)d_in[5];
    const float* A_imag      = (const float*)d_in[6];
    const float* D           = (const float*)d_in[7];
    const float* film_w      = (const float*)d_in[8];
    const float* film_b      = (const float*)d_in[9];
    float* out = (float*)d_out;

    char* w = (char*)d_ws;
    bf16*   y      = (bf16*)w;                    // 33,554,432 B
    short*  Qh     = (short*)(w + 33554432);      //  1,048,576 B
    short*  Pmh    = (short*)(w + 34603008);      //  1,048,576 B
    short*  Pml    = (short*)(w + 35651584);      //  1,048,576 B
    short*  Klh    = (short*)(w + 36700160);      //    524,288 B
    short*  Kll    = (short*)(w + 37224448);      //    524,288 B
    float*  rLtab  = (float*)(w + 37748736);      //     32,768 B
    float*  rStab  = (float*)(w + 37781504);      //     32,768 B
    double* stats  = (double*)(w + 37814272);     //      1,024 B   (~37.8 MB)

    hipMemsetAsync(stats, 0, 1024, stream);
    hipLaunchKernelGGL(k0_setup, dim3(64),   dim3(256), 0, stream,
                       log_dt, C_ri, log_A_real, A_imag, D,
                       rLtab, rStab, Qh, Pmh, Pml, Klh, Kll);
    hipLaunchKernelGGL(k_fused,  dim3(1024), dim3(256), 0, stream,
                       u, length, rLtab, rStab, Qh, Pmh, Pml, Klh, Kll, y, stats);
    hipLaunchKernelGGL(k4_final, dim3(8192), dim3(256), 0, stream,
                       u, y, cond, film_w, film_b, stats, out);
}

// Round 15
// 104.401 us; speedup vs baseline: 1.5986x; 1.0335x over previous
//
#include <hip/hip_runtime.h>
#include <hip/hip_bf16.h>

typedef __hip_bfloat16 bf16;
typedef __attribute__((ext_vector_type(8))) short s16x8;
typedef __attribute__((ext_vector_type(4))) float f32x4;

// Y-staging swizzle on 128B rows (R8-proven, 16B granule)
#define SWZY(c) ((((c) ^ ((c) >> 3) ^ ((c) >> 4)) & 7) << 4)
// S/carry region swizzle (R13/R14-proven: conflicts 5.4M -> 786K).
// Local mode ml (0..31) of row c lives at dword DWP(ml,c); 16B blocks stay
// contiguous so gemm3's b128 reads work.
#define GB(c)  ((((c) ^ ((c) >> 3) ^ ((c) >> 5)) & 7))
#define DWP(ml, c) (((ml) & 3) | (((((ml) >> 2) ^ GB(c)) & 7) << 2))

__device__ __forceinline__ unsigned short f2b(float x){
    __hip_bfloat16 h = __float2bfloat16(x);
    return __builtin_bit_cast(unsigned short, h);
}
__device__ __forceinline__ float b2f(unsigned short s){
    unsigned int u = (unsigned int)s << 16;
    return __builtin_bit_cast(float, u);
}

// ---------------- K0: per-h tables via direct complex exp ------------------
// Qh[h][n2=128][t=64]     : Q[2n][t]=Re r^{63-t}, Q[2n+1][t]=Im r^{63-t} (bf16)
// Pmh/Pml[h][j=64][n2=128]: Pm[j][2n]=Re(2Ck r^{j+1}), [2n+1]=-Im(...)   (hi+lo)
// Klh/Kll[h][j=64][t=64]  : Kd[j-t] (t<=j) + D*delta(t==j)  [row j]      (hi+lo)
// rLtab[h][n][2]=r^64 ; rStab[h][n][2]=r^4096  (f32, scan: 64-chunk segments)
__global__ __launch_bounds__(256) void k0_setup(const float* __restrict__ log_dt,
        const float* __restrict__ C_ri, const float* __restrict__ log_A_real,
        const float* __restrict__ A_imag, const float* __restrict__ Dp,
        float* __restrict__ rLtab, float* __restrict__ rStab,
        short* __restrict__ Qh,
        short* __restrict__ Pmh, short* __restrict__ Pml,
        short* __restrict__ Klh, short* __restrict__ Kll)
{
    __shared__ float arr[64][65];   // Pm_re staging: arr[j][n] = Re(2Ck r^{j+1})
    __shared__ float a0[64];        // 2*Re(Ck)
    __shared__ float kd[64];
    int h = blockIdx.x;
    int tid = threadIdx.x;
    int n = tid & 63, g = tid >> 6;
    int hn = h * 64 + n;
    double dtd  = exp((double)log_dt[h]);
    float  Aref = -expf(log_A_real[hn]);
    double Ared = (double)Aref;
    double Aimd = (double)A_imag[hn];
    double adt  = Aimd * dtd;                 // angle per unit exponent
    float  mdt  = (float)(Ared * dtd);        // log-magnitude per unit exponent
    auto cexp = [&](float e, float& re, float& im){
        double a = adt * (double)e;
        double k = floor(a * 0.15915494309189535);
        float ang = (float)(a - k * 6.283185307179586);
        float si, co;
        __sincosf(ang, &si, &co);
        float mag = expf(mdt * e);
        re = mag * co; im = mag * si;
    };
    // Ck = C * (r-1)/A
    float rre, rim; cexp(1.f, rre, rim);
    float Cre = C_ri[2 * hn], Cim = C_ri[2 * hn + 1];
    float emre = rre - 1.f, emim = rim;
    float inva2 = 1.f / (Aref * Aref + (float)(Aimd * Aimd));
    float qre_ = (emre * Aref + emim * (float)Aimd) * inva2;
    float qim_ = (emim * Aref - emre * (float)Aimd) * inva2;
    float ckre = Cre * qre_ - Cim * qim_;
    float ckim = Cre * qim_ + Cim * qre_;
    // Q rows 2n,2n+1 for t in [16g,16g+16)
    {
        short* q0 = Qh + (size_t)h * 8192 + (2 * n) * 64;
        short* q1 = q0 + 64;
        for (int t = 16 * g; t < 16 * g + 16; ++t) {
            float pre, pim; cexp((float)(63 - t), pre, pim);
            q0[t] = (short)f2b(pre);
            q1[t] = (short)f2b(pim);
        }
    }
    if (g == 0) {   // r^64
        float pre, pim; cexp(64.f, pre, pim);
        rLtab[2 * hn] = pre; rLtab[2 * hn + 1] = pim;
    }
    if (g == 1) {   // r^4096 (segment hop: 64 chunks x 64)
        float pre, pim; cexp(4096.f, pre, pim);
        rStab[2 * hn] = pre; rStab[2 * hn + 1] = pim;
    }
    if (g == 2) a0[n] = 2.f * ckre;
    // Pm rows j in [16g,16g+16)
    {
        short* pmh = Pmh + (size_t)h * 8192;
        short* pml = Pml + (size_t)h * 8192;
        for (int j = 16 * g; j < 16 * g + 16; ++j) {
            float pre, pim; cexp((float)(j + 1), pre, pim);
            float wre = 2.f * (ckre * pre - ckim * pim);
            float wim = 2.f * (ckre * pim + ckim * pre);
            unsigned short h0 = f2b(wre), h1 = f2b(-wim);
            pmh[j * 128 + 2 * n]     = (short)h0;
            pml[j * 128 + 2 * n]     = (short)f2b(wre - b2f(h0));
            pmh[j * 128 + 2 * n + 1] = (short)h1;
            pml[j * 128 + 2 * n + 1] = (short)f2b(-wim - b2f(h1));
            arr[j][n] = wre;
        }
    }
    __syncthreads();
    if (tid < 64) {                 // Kd[d]
        int d = tid;
        float s = 0.f;
        if (d == 0) { for (int k = 0; k < 64; ++k) s += a0[k]; }
        else        { for (int k = 0; k < 64; ++k) s += arr[d - 1][k]; }
        kd[d] = s;
    }
    __syncthreads();
    // Klow ROW j=n (storage [j][t]), D on diagonal
    {
        float Dh = Dp[h];
        short* klh = Klh + (size_t)h * 4096 + n * 64;   // row j=n
        short* kll = Kll + (size_t)h * 4096 + n * 64;
        for (int t = 16 * g; t < 16 * g + 16; ++t) {
            if (t <= n) {
                float v = kd[n - t] + ((t == n) ? Dh : 0.f);
                unsigned short h0 = f2b(v);
                klh[t] = (short)h0;
                kll[t] = (short)f2b(v - b2f(h0));
            } else { klh[t] = 0; kll[t] = 0; }
        }
    }
}

// ------- fused: {conv+gemm1x2} | {unified scan} | {gemm3x2+Ystage} | epi ----
// block=(b,h); 4 waves; wave w owns c-rows [64w,64w+64).
// LDS = 64KB: TWO 32KB S/carry regions (half 0 and half 1), in-place S->carry.
// 3 barriers (was 6). Registers cap at 2 blocks/CU anyway (192/wave), and
// 2 x 64KB = 128KB <= 160KB, so occupancy is unchanged by the bigger LDS.
// __launch_bounds__(256,2): the ONLY no-spill setting (4x confirmed:
// R6/R9/R11/R13 spill at higher 2nd arg; R7/R8/R12/R14 clean at 2).
__global__ __launch_bounds__(256, 2) void k_fused(const float* __restrict__ u,
        const int* __restrict__ length,
        const float* __restrict__ rLtab, const float* __restrict__ rStab,
        const short* __restrict__ Qh,
        const short* __restrict__ Pmh, const short* __restrict__ Pml,
        const short* __restrict__ Klh, const short* __restrict__ Kll,
        bf16* __restrict__ y, double* __restrict__ stats)
{
    __shared__ __align__(16) unsigned char lds[65536];
    int bh = blockIdx.x;
    int b = bh >> 6, h = bh & 63;
    int tid = threadIdx.x;
    int w = tid >> 6, lane = tid & 63;
    int lo = lane & 15, hi = lane >> 4;
    int len = length[b];
    const float* ub = u + (size_t)bh * 16384;

    // ---- X fragments, hi+lo split (masked u)
    s16x8 xh[4][2], xl[4][2];
    #pragma unroll
    for (int ct = 0; ct < 4; ++ct) {
        int c = w * 64 + ct * 16 + lo;
        #pragma unroll
        for (int kt = 0; kt < 2; ++kt) {
            int gidx = c * 64 + kt * 32 + hi * 8;
            float4 v0 = *(const float4*)(ub + gidx);
            float4 v1 = *(const float4*)(ub + gidx + 4);
            float xv[8] = {v0.x, v0.y, v0.z, v0.w, v1.x, v1.y, v1.z, v1.w};
            s16x8 fh, fl;
            #pragma unroll
            for (int e = 0; e < 8; ++e) {
                float xm = (gidx + e < len) ? xv[e] : 0.f;
                unsigned short h0 = f2b(xm);
                fh[e] = (short)h0;
                fl[e] = (short)f2b(xm - b2f(h0));
            }
            xh[ct][kt] = fh;
            xl[ct][kt] = fl;
        }
    }

    // ---- phase A: conv (+D baked) and BOTH gemm1 halves, no barriers inside
    f32x4 acc[4][4];
    #pragma unroll
    for (int ct = 0; ct < 4; ++ct)
        #pragma unroll
        for (int jt = 0; jt < 4; ++jt)
            acc[ct][jt] = f32x4{0.f, 0.f, 0.f, 0.f};
    {
        const short* klhb = Klh + (size_t)h * 4096;
        const short* kllb = Kll + (size_t)h * 4096;
        #pragma unroll
        for (int kt = 0; kt < 2; ++kt) {
            #pragma unroll
            for (int jt = 0; jt < 4; ++jt) {
                s16x8 kfh = *(const s16x8*)(klhb + (jt * 16 + lo) * 64 + kt * 32 + hi * 8);
                s16x8 kfl = *(const s16x8*)(kllb + (jt * 16 + lo) * 64 + kt * 32 + hi * 8);
                #pragma unroll
                for (int ct = 0; ct < 4; ++ct) {
                    acc[ct][jt] = __builtin_amdgcn_mfma_f32_16x16x32_bf16(xh[ct][kt], kfh, acc[ct][jt], 0, 0, 0);
                    acc[ct][jt] = __builtin_amdgcn_mfma_f32_16x16x32_bf16(xh[ct][kt], kfl, acc[ct][jt], 0, 0, 0);
                    acc[ct][jt] = __builtin_amdgcn_mfma_f32_16x16x32_bf16(xl[ct][kt], kfh, acc[ct][jt], 0, 0, 0);
                }
            }
        }
    }
    #pragma unroll
    for (int hh = 0; hh < 2; ++hh) {    // gemm1 both halves (qh*xl dropped)
        const short* qb = Qh + (size_t)h * 8192 + (hh * 64) * 64;
        unsigned char* base = lds + hh * 32768;
        #pragma unroll
        for (int mt = 0; mt < 4; ++mt) {
            s16x8 q0 = *(const s16x8*)(qb + (mt * 16 + lo) * 64 + hi * 8);
            s16x8 q1 = *(const s16x8*)(qb + (mt * 16 + lo) * 64 + 32 + hi * 8);
            #pragma unroll
            for (int ct = 0; ct < 4; ++ct) {
                f32x4 sc = f32x4{0.f, 0.f, 0.f, 0.f};
                sc = __builtin_amdgcn_mfma_f32_16x16x32_bf16(q0, xh[ct][0], sc, 0, 0, 0);
                sc = __builtin_amdgcn_mfma_f32_16x16x32_bf16(q1, xh[ct][1], sc, 0, 0, 0);
                int c = w * 64 + ct * 16 + lo;
                int ml0 = 8 * mt + 2 * hi;
                unsigned int p0 = (unsigned)f2b(sc[0]) | ((unsigned)f2b(sc[1]) << 16);
                unsigned int p1 = (unsigned)f2b(sc[2]) | ((unsigned)f2b(sc[3]) << 16);
                unsigned long long pp = (unsigned long long)p0 | ((unsigned long long)p1 << 32);
                *(unsigned long long*)(base + c * 128 + DWP(ml0, c) * 4) = pp;
            }
        }
    }
    __syncthreads();   // B1

    // ---- phase B: unified scan over ALL 64 modes.
    // thread: mode m = tid>>2 (0..63), segment s = tid&3 (64 chunks each);
    // in-place carries (each (row,dword) owned by exactly one thread).
    {
        int m = tid >> 2, s = tid & 3;
        int hh = m >> 5, ml = m & 31;
        unsigned char* base = lds + hh * 32768;
        int gm = (h * 64 + m) * 2;
        float r64re = rLtab[gm], r64im = rLtab[gm + 1];
        float pre = rStab[gm],  pim = rStab[gm + 1];     // r^4096
        // pass 1: segment end-state (64 chunks)
        float ere = 0.f, eim = 0.f;
        #pragma unroll
        for (int i = 0; i < 64; ++i) {
            int c = 64 * s + i;
            unsigned int v = *(const unsigned int*)(base + c * 128 + DWP(ml, c) * 4);
            float vre = b2f((unsigned short)v);
            float vim = b2f((unsigned short)(v >> 16));
            float nre = fmaf(r64re, ere, fmaf(-r64im, eim, vre));
            eim = fmaf(r64re, eim, fmaf(r64im, ere, vim));
            ere = nre;
        }
        // in-wave Kogge-Stone over 4 segments (d = 1,2; p <- p^2 each step)
        #pragma unroll
        for (int d = 1; d < 4; d <<= 1) {
            float orr = __shfl(ere, (lane - d) & 63, 64);
            float oii = __shfl(eim, (lane - d) & 63, 64);
            if (s >= d) {
                float nre = fmaf(pre, orr, fmaf(-pim, oii, ere));
                eim = fmaf(pre, oii, fmaf(pim, orr, eim));
                ere = nre;
            }
            float t2 = pre * pre - pim * pim;
            pim = 2.f * pre * pim;
            pre = t2;
        }
        // exclusive carry-in = inclusive of segment s-1
        float cire = __shfl(ere, (lane - 1) & 63, 64);
        float ciim = __shfl(eim, (lane - 1) & 63, 64);
        if (s == 0) { cire = 0.f; ciim = 0.f; }
        // pass 2: overwrite S dword with carry
        #pragma unroll
        for (int i = 0; i < 64; ++i) {
            int c = 64 * s + i;
            unsigned char* p = base + c * 128 + DWP(ml, c) * 4;
            unsigned int v = *(const unsigned int*)p;
            float vre = b2f((unsigned short)v);
            float vim = b2f((unsigned short)(v >> 16));
            *(unsigned int*)p = (unsigned)f2b(cire) | ((unsigned)f2b(ciim) << 16);
            float nre = fmaf(r64re, cire, fmaf(-r64im, ciim, vre));
            ciim = fmaf(r64re, ciim, fmaf(r64im, cire, vim));
            cire = nre;
        }
    }
    __syncthreads();   // B2

    // ---- phase C: gemm3 both halves, then Y staging (all wave-local rows;
    // same-wave LDS program order makes the region reuse safe without barrier)
    #pragma unroll
    for (int hh = 0; hh < 2; ++hh) {
        const short* pmhb = Pmh + (size_t)h * 8192 + hh * 64;
        const short* pmlb = Pml + (size_t)h * 8192 + hh * 64;
        unsigned char* base = lds + hh * 32768;
        #pragma unroll
        for (int kt2 = 0; kt2 < 2; ++kt2) {
            s16x8 af[4];
            #pragma unroll
            for (int ct = 0; ct < 4; ++ct) {
                int c = w * 64 + ct * 16 + lo;
                int blk = (4 * kt2 + hi) ^ GB(c);
                af[ct] = *(const s16x8*)(base + c * 128 + blk * 16);
            }
            #pragma unroll
            for (int jt = 0; jt < 4; ++jt) {
                s16x8 pfh = *(const s16x8*)(pmhb + (jt * 16 + lo) * 128 + kt2 * 32 + hi * 8);
                s16x8 pfl = *(const s16x8*)(pmlb + (jt * 16 + lo) * 128 + kt2 * 32 + hi * 8);
                #pragma unroll
                for (int ct = 0; ct < 4; ++ct) {
                    acc[ct][jt] = __builtin_amdgcn_mfma_f32_16x16x32_bf16(af[ct], pfh, acc[ct][jt], 0, 0, 0);
                    acc[ct][jt] = __builtin_amdgcn_mfma_f32_16x16x32_bf16(af[ct], pfl, acc[ct][jt], 0, 0, 0);
                }
            }
        }
    }
    #pragma unroll
    for (int ct = 0; ct < 4; ++ct) {    // Y staging into region 0 (wave-local)
        #pragma unroll
        for (int jt = 0; jt < 4; ++jt) {
            int j = jt * 16 + lo;
            #pragma unroll
            for (int rg = 0; rg < 4; ++rg) {
                int c = w * 64 + ct * 16 + hi * 4 + rg;
                *(unsigned short*)(lds + c * 128 + ((2 * j) ^ SWZY(c))) = f2b(acc[ct][jt][rg]);
            }
        }
    }
    __syncthreads();   // B3

    // ---- epilogue: mask, coalesced y store, f32 stats -> f64 atomics
    float s1 = 0.f, s2 = 0.f;
    short* yg = (short*)y + (size_t)bh * 16384;
    #pragma unroll
    for (int k = 0; k < 8; ++k) {
        int eidx = (k * 256 + tid) * 8;
        int row = eidx >> 6;
        int byt = ((eidx & 63) * 2) ^ SWZY(row);
        s16x8 yv = *(const s16x8*)(lds + row * 128 + byt);
        s16x8 o;
        #pragma unroll
        for (int e = 0; e < 8; ++e) {
            float vv = b2f((unsigned short)yv[e]);
            vv = (eidx + e < len) ? vv : 0.f;
            o[e] = (short)f2b(vv);
            s1 += vv;
            s2 = fmaf(vv, vv, s2);
        }
        *(s16x8*)(yg + eidx) = o;
    }
    #pragma unroll
    for (int off = 32; off > 0; off >>= 1) {
        s1 += __shfl_down(s1, off, 64);
        s2 += __shfl_down(s2, off, 64);
    }
    if (lane == 0) {
        atomicAdd(&stats[2 * h],     (double)s1);
        atomicAdd(&stats[2 * h + 1], (double)s2);
    }
}

// ---------------- K4: layernorm + FiLM + tanh + residual (8 elems/thread) --
__global__ __launch_bounds__(256) void k4_final(const float* __restrict__ u,
        const bf16* __restrict__ y, const float* __restrict__ cond,
        const float* __restrict__ fw, const float* __restrict__ fb,
        const double* __restrict__ stats, float* __restrict__ out)
{
    int tid = threadIdx.x;
    size_t idx8 = ((size_t)blockIdx.x * 256 + tid) * 8;
    int bh = (int)(idx8 >> 14);
    int b = bh >> 6, h = bh & 63;
    __shared__ float gg[2];
    if (tid == 0) {
        float g = fb[h], bb = fb[64 + h];
        #pragma unroll
        for (int k = 0; k < 3; ++k) {
            g  = fmaf(cond[b * 3 + k], fw[h * 3 + k], g);
            bb = fmaf(cond[b * 3 + k], fw[(64 + h) * 3 + k], bb);
        }
        gg[0] = g; gg[1] = bb;
    }
    __syncthreads();
    double inv = 1.0 / (16.0 * 16384.0);
    double mean_d = stats[2 * h] * inv;
    double var_d  = stats[2 * h + 1] * inv - mean_d * mean_d;
    float mean = (float)mean_d;
    float rstd = rsqrtf((float)var_d + 1e-5f);
    float gv = gg[0], bv = gg[1];
    float4 u0 = *(const float4*)(u + idx8);
    float4 u1 = *(const float4*)(u + idx8 + 4);
    s16x8 yv = *(const s16x8*)((const short*)y + idx8);
    float uv[8] = {u0.x, u0.y, u0.z, u0.w, u1.x, u1.y, u1.z, u1.w};
    float ov[8];
    #pragma unroll
    for (int e = 0; e < 8; ++e) {
        float z = fmaf((b2f((unsigned short)yv[e]) - mean) * rstd, gv, bv);
        ov[e] = uv[e] + tanhf(z);
    }
    *(float4*)(out + idx8)     = float4{ov[0], ov[1], ov[2], ov[3]};
    *(float4*)(out + idx8 + 4) = float4{ov[4], ov[5], ov[6], ov[7]};
}

// ---------------------------------------------------------------------------
extern "C" void kernel_launch(void* const* d_in, const int* in_sizes, int n_in,
                              void* d_out, int out_size, void* d_ws, size_t ws_size,
                              hipStream_t stream)
{
    const float* u           = (const float*)d_in[0];
    const float* cond        = (const float*)d_in[1];
    const int*   length      = (const int*)  d_in[2];
    const float* log_dt      = (const float*)d_in[3];
    const float* C_ri        = (const float*)d_in[4];
    const float* log_A_real  = (const float*)d_in[5];
    const float* A_imag      = (const float*)d_in[6];
    const float* D           = (const float*)d_in[7];
    const float* film_w      = (const float*)d_in[8];
    const float* film_b      = (const float*)d_in[9];
    float* out = (float*)d_out;

    char* w = (char*)d_ws;
    bf16*   y      = (bf16*)w;                    // 33,554,432 B
    short*  Qh     = (short*)(w + 33554432);      //  1,048,576 B
    short*  Pmh    = (short*)(w + 34603008);      //  1,048,576 B
    short*  Pml    = (short*)(w + 35651584);      //  1,048,576 B
    short*  Klh    = (short*)(w + 36700160);      //    524,288 B
    short*  Kll    = (short*)(w + 37224448);      //    524,288 B
    float*  rLtab  = (float*)(w + 37748736);      //     32,768 B
    float*  rStab  = (float*)(w + 37781504);      //     32,768 B
    double* stats  = (double*)(w + 37814272);     //      1,024 B   (~37.8 MB)

    hipMemsetAsync(stats, 0, 1024, stream);
    hipLaunchKernelGGL(k0_setup, dim3(64),   dim3(256), 0, stream,
                       log_dt, C_ri, log_A_real, A_imag, D,
                       rLtab, rStab, Qh, Pmh, Pml, Klh, Kll);
    hipLaunchKernelGGL(k_fused,  dim3(1024), dim3(256), 0, stream,
                       u, length, rLtab, rStab, Qh, Pmh, Pml, Klh, Kll, y, stats);
    hipLaunchKernelGGL(k4_final, dim3(8192), dim3(256), 0, stream,
                       u, y, cond, film_w, film_b, stats, out);
}